// Round 13
// baseline (218.987 us; speedup 1.0000x reference)
//
#include <hip/hip_runtime.h>
#include <math.h>

#define Bdim  2
#define Nseq  2048
#define Dmod  512
#define Hn    8
#define DHd   64
#define HID   2730
#define HHALF 1365
#define HC    1408      // combined hidden, padded (22*64)
#define NPACK 2816      // packed fc1 output cols (2*HC)
#define ROWS  4096      // Bdim*Nseq
#define NSPLIT 2        // attention split-K (r7-frozen config)

typedef __bf16 bf16x8 __attribute__((ext_vector_type(8)));
typedef __bf16 bf16x4 __attribute__((ext_vector_type(4)));
typedef float  f32x4  __attribute__((ext_vector_type(4)));

__device__ __forceinline__ void glds16(const __bf16* g, __bf16* l) {
    __builtin_amdgcn_global_load_lds(
        (const __attribute__((address_space(1))) void*)g,
        (__attribute__((address_space(3))) void*)l, 16, 0, 0);
}

// weight segment sizes
#define SEG0 (1536*512)    // wqkv
#define SEG1 (512*512)     // wo
#define SEG2 (NPACK*512)   // wfc1p
#define SEG3 (512*HC)      // wfc2p
#define WQKV_BLOCKS (SEG0 / 256)           // 3072
#define ZERO_BLOCKS 32                     // rstats 4096*2 floats
#define REST_BLOCKS ((SEG1 + SEG2 + SEG3) / 256)   // 9472 = 37 * 256-slices of (32x8)
#define REST_Z (REST_BLOCKS / (32 * 8))    // 37

// ---------------- LN core (row=512, 256 threads) ----------------
__device__ __forceinline__ void ln_core(
    int tid, float vx, float vy, const float* __restrict__ w,
    const float* __restrict__ b, __bf16* __restrict__ orow)
{
    float s  = vx + vy;
    float sq = vx * vx + vy * vy;
#pragma unroll
    for (int m = 1; m < 64; m <<= 1) {
        s  += __shfl_xor(s, m, 64);
        sq += __shfl_xor(sq, m, 64);
    }
    __shared__ float ss[4], ssq[4];
    const int wv = tid >> 6;
    if ((tid & 63) == 0) { ss[wv] = s; ssq[wv] = sq; }
    __syncthreads();
    s  = ss[0] + ss[1] + ss[2] + ss[3];
    sq = ssq[0] + ssq[1] + ssq[2] + ssq[3];
    const float mean = s * (1.0f / Dmod);
    const float var  = sq * (1.0f / Dmod) - mean * mean;
    const float rstd = rsqrtf(var + 1e-5f);
    float2 wv2 = *(const float2*)(w + tid * 2);
    float2 bv2 = *(const float2*)(b + tid * 2);
    orow[0] = (__bf16)((vx - mean) * rstd * wv2.x + bv2.x);
    orow[1] = (__bf16)((vy - mean) * rstd * wv2.y + bv2.y);
}

// ---------------- prep: wqkv conversion + zero rstats + LN1 ----------------
__global__ __launch_bounds__(256) void prep_kernel(
    const float* __restrict__ q_w, const float* __restrict__ k_w,
    const float* __restrict__ v_w, __bf16* __restrict__ wqkv,
    const float* __restrict__ x, const float* __restrict__ ln1w,
    const float* __restrict__ ln1b, __bf16* __restrict__ xn,
    float* __restrict__ rstats)
{
    if (blockIdx.x < WQKV_BLOCKS) {
        int idx = blockIdx.x * 256 + threadIdx.x;
        int n = idx >> 9, k = idx & 511;
        float v = (n < 512) ? q_w[n * 512 + k]
                : (n < 1024) ? k_w[(n - 512) * 512 + k]
                : v_w[(n - 1024) * 512 + k];
        wqkv[idx] = (__bf16)v;
        return;
    }
    if (blockIdx.x < WQKV_BLOCKS + ZERO_BLOCKS) {
        rstats[(blockIdx.x - WQKV_BLOCKS) * 256 + threadIdx.x] = 0.0f;
        return;
    }
    const int row = blockIdx.x - WQKV_BLOCKS - ZERO_BLOCKS, tid = threadIdx.x;
    float2 v = *(const float2*)(x + (size_t)row * Dmod + tid * 2);
    ln_core(tid, v.x, v.y, ln1w, ln1b, xn + (size_t)row * Dmod + tid * 2);
}

// ---------------- 64x64 residual GEMM, 8 waves, K-parallel x2, XOR-swizzled LDS ----------------
// MODE 0 (o-proj): A = merged attention partials; res fp32; out bf16 + row-stats atomics.
// MODE 1 (fc2):    A = direct bf16 via glds16;    res bf16; out fp32.
template<int MODE>
__global__ __launch_bounds__(512) void gemm_res(
    const __bf16* __restrict__ A, int lda,
    const __bf16* __restrict__ opA, const float* __restrict__ lpA,
    const __bf16* __restrict__ Bw, int ldb,
    const float* __restrict__ bias, int K,
    void* __restrict__ outp, const void* __restrict__ resp,
    const float* __restrict__ g, float* __restrict__ rstats)
{
    __shared__ __bf16 smem[2 * 64 * 64];
    __bf16* As = smem;
    __bf16* Bs = smem + 64 * 64;
    const int tid  = threadIdx.x;
    const int wave = tid >> 6, lane = tid & 63;
    const int t    = lane & 15, quad = lane >> 4;
    const int kg   = wave >> 2, wv = wave & 3;
    const int m0   = blockIdx.x * 64;
    const int n0   = blockIdx.y * 64;

    const int srow = tid >> 3;
    const int gch  = ((tid & 7) ^ (srow & 7)) * 8;
    const int grow = m0 + srow;
    const int bI   = grow >> 11, nn = grow & 2047;
    const __bf16* aptr = A  + (size_t)grow * lda + gch;
    const __bf16* bptr = Bw + (size_t)(n0 + srow) * ldb + gch;

    const int arow = wv * 16 + t;
    const int aoff = arow * 64 + (((kg * 4 + quad) ^ (arow & 7)) * 8);
    int boffs[4];
#pragma unroll
    for (int ct = 0; ct < 4; ++ct) {
        int brow = ct * 16 + t;
        boffs[ct] = brow * 64 + (((kg * 4 + quad) ^ (brow & 7)) * 8);
    }

    f32x4 acc[4] = {};
    for (int k0 = 0; k0 < K; k0 += 64) {
        __syncthreads();
        if (MODE == 0) {
            const int kk = k0 + gch;
            const int h = kk >> 6;
            float l = lpA[((size_t)(bI * Hn) + h) * Nseq + nn]
                    + lpA[((size_t)((Bdim + bI) * Hn) + h) * Nseq + nn];
            float rl = __builtin_amdgcn_rcpf(l);
            bf16x8 a0 = *(const bf16x8*)(opA + (size_t)grow * Dmod + kk);
            bf16x8 a1 = *(const bf16x8*)(opA + ((size_t)ROWS + grow) * Dmod + kk);
            bf16x8 mg;
#pragma unroll
            for (int j = 0; j < 8; ++j)
                mg[j] = (__bf16)(((float)a0[j] + (float)a1[j]) * rl);
            *(bf16x8*)(As + tid * 8) = mg;
        } else {
            glds16(aptr + k0, As + tid * 8);
        }
        glds16(bptr + k0, Bs + tid * 8);
        __syncthreads();
        bf16x8 a = *(const bf16x8*)(As + aoff);
#pragma unroll
        for (int ct = 0; ct < 4; ++ct) {
            bf16x8 b = *(const bf16x8*)(Bs + boffs[ct]);
            acc[ct] = __builtin_amdgcn_mfma_f32_16x16x32_bf16(a, b, acc[ct], 0, 0, 0);
        }
    }

    __syncthreads();
    if (kg == 1) {
        float* dst = (float*)smem + ((size_t)wv * 64 + lane) * 16;
#pragma unroll
        for (int ct = 0; ct < 4; ++ct) *(f32x4*)(dst + ct * 4) = acc[ct];
    }
    __syncthreads();
    if (kg == 0) {
        const float* src = (const float*)smem + ((size_t)wv * 64 + lane) * 16;
        const int row_base = m0 + wv * 16 + quad * 4;
        float rsum[4] = {0.f, 0.f, 0.f, 0.f};
        float rsq[4]  = {0.f, 0.f, 0.f, 0.f};
#pragma unroll
        for (int ct = 0; ct < 4; ++ct) {
            f32x4 other = *(const f32x4*)(src + ct * 4);
            const int col = n0 + ct * 16 + t;
            const float bb = bias[col];
#pragma unroll
            for (int r = 0; r < 4; ++r) {
                const int row = row_base + r;
                const float v = (acc[ct][r] + other[r] + bb) * g[col];
                if (MODE == 0) {
                    float rv = ((const float*)resp)[(size_t)row * Dmod + col];
                    __bf16 xv = (__bf16)(rv + v);
                    ((__bf16*)outp)[(size_t)row * Dmod + col] = xv;
                    float xf = (float)xv;
                    rsum[r] += xf;
                    rsq[r]  += xf * xf;
                } else {
                    float rv = (float)((const __bf16*)resp)[(size_t)row * Dmod + col];
                    ((float*)outp)[(size_t)row * Dmod + col] = rv + v;
                }
            }
        }
        if (MODE == 0) {
            // reduce the 16 t-lanes (same wv,quad => same rows), then one atomic per row
#pragma unroll
            for (int r = 0; r < 4; ++r) {
#pragma unroll
                for (int msk = 1; msk < 16; msk <<= 1) {
                    rsum[r] += __shfl_xor(rsum[r], msk, 64);
                    rsq[r]  += __shfl_xor(rsq[r],  msk, 64);
                }
            }
            if (t == 0) {
#pragma unroll
                for (int r = 0; r < 4; ++r) {
                    atomicAdd(&rstats[(size_t)(row_base + r) * 2],     rsum[r]);
                    atomicAdd(&rstats[(size_t)(row_base + r) * 2 + 1], rsq[r]);
                }
            }
        }
    }
}

// ---------------- 128x128 QKV GEMM (BK=32); V written transposed via LDS ----------------
#define LDT 136
__global__ __launch_bounds__(256) void qkv_gemm128(
    const __bf16* __restrict__ A, const __bf16* __restrict__ W,
    const float* __restrict__ qb_, const float* __restrict__ kb_,
    const float* __restrict__ vb_,
    __bf16* __restrict__ qk, __bf16* __restrict__ vtg)
{
    __shared__ __bf16 smem[64 * LDT];
    __bf16* As = smem;
    __bf16* Bs = smem + 4096;
    const int tid  = threadIdx.x;
    const int wave = tid >> 6, lane = tid & 63;
    const int t    = lane & 15, quad = lane >> 4;
    const int m0   = blockIdx.x * 128, n0 = blockIdx.y * 128;
    const int mr   = (wave & 1) * 64,  nr = (wave >> 1) * 64;
    const int ra0 = tid >> 2,          ca0 = (tid & 3) * 8;
    const int ra1 = (tid + 256) >> 2,  ca1 = (tid & 3) * 8;

    f32x4 acc[4][4] = {};

    for (int k0 = 0; k0 < Dmod; k0 += 32) {
        __syncthreads();
        glds16(A + (size_t)(m0 + ra0) * Dmod + k0 + ca0, As + tid * 8);
        glds16(A + (size_t)(m0 + ra1) * Dmod + k0 + ca1, As + (tid + 256) * 8);
        glds16(W + (size_t)(n0 + ra0) * Dmod + k0 + ca0, Bs + tid * 8);
        glds16(W + (size_t)(n0 + ra1) * Dmod + k0 + ca1, Bs + (tid + 256) * 8);
        __syncthreads();
        bf16x8 af[4], bfr[4];
#pragma unroll
        for (int mi = 0; mi < 4; ++mi)
            af[mi] = *(const bf16x8*)(As + (mr + mi * 16 + t) * 32 + quad * 8);
#pragma unroll
        for (int ni = 0; ni < 4; ++ni)
            bfr[ni] = *(const bf16x8*)(Bs + (nr + ni * 16 + t) * 32 + quad * 8);
#pragma unroll
        for (int mi = 0; mi < 4; ++mi)
#pragma unroll
            for (int ni = 0; ni < 4; ++ni)
                acc[mi][ni] = __builtin_amdgcn_mfma_f32_16x16x32_bf16(af[mi], bfr[ni], acc[mi][ni], 0, 0, 0);
    }

    const int y = blockIdx.y;
    if (y < 8) {
#pragma unroll
        for (int mi = 0; mi < 4; ++mi) {
            const int row_base = m0 + mr + mi * 16 + quad * 4;
#pragma unroll
            for (int ni = 0; ni < 4; ++ni) {
                const int col = n0 + nr + ni * 16 + t;
                const float bb = (col < 512) ? qb_[col] : kb_[col - 512];
#pragma unroll
                for (int r = 0; r < 4; ++r)
                    qk[(size_t)(row_base + r) * 1024 + col] = (__bf16)(acc[mi][ni][r] + bb);
            }
        }
    } else {
        const int tok0 = m0 & 2047;
        const int bI   = m0 >> 11;
#pragma unroll
        for (int half = 0; half < 2; ++half) {
            __syncthreads();
            if ((wave >> 1) == half) {
#pragma unroll
                for (int ni = 0; ni < 4; ++ni) {
                    const int dh = ni * 16 + t;
                    const float bb = vb_[(y - 8) * 128 + half * 64 + dh];
#pragma unroll
                    for (int mi = 0; mi < 4; ++mi) {
                        const int n = mr + mi * 16 + quad * 4;
                        bf16x4 pk;
#pragma unroll
                        for (int r = 0; r < 4; ++r) pk[r] = (__bf16)(acc[mi][ni][r] + bb);
                        *(bf16x4*)(smem + dh * LDT + n) = pk;
                    }
                }
            }
            __syncthreads();
            const int hh = (y - 8) * 2 + half;
            const size_t rowbase = (size_t)(bI * 8 + hh) * 64;
#pragma unroll
            for (int j = 0; j < 4; ++j) {
                int chunk = tid + j * 256;
                int dr = chunk >> 4, cc = (chunk & 15) * 8;
                bf16x8 vv = *(const bf16x8*)(smem + dr * LDT + cc);
                *(bf16x8*)(vtg + (rowbase + dr) * Nseq + tok0 + cc) = vv;
            }
        }
    }
}

// ---------------- 128x128 fc1 GEMM (BK=32) with fused LN2 (A-staging) + SwiGLU epilogue ----------------
__global__ __launch_bounds__(256) void fc1_gemm128(
    const __bf16* __restrict__ x1, const float* __restrict__ rstats,
    const float* __restrict__ ln2w, const float* __restrict__ ln2b,
    const __bf16* __restrict__ W,
    const float* __restrict__ fc1_b_, __bf16* __restrict__ out)
{
    __shared__ __bf16 As[128 * 32];
    __shared__ __bf16 Bs[128 * 32];
    const int tid  = threadIdx.x;
    const int wave = tid >> 6, lane = tid & 63;
    const int t    = lane & 15, quad = lane >> 4;
    const int m0   = blockIdx.x * 128, n0 = blockIdx.y * 128;
    const int mr   = (wave & 1) * 64,  nr = (wave >> 1) * 64;
    const int ra0 = tid >> 2,          ca0 = (tid & 3) * 8;
    const int ra1 = (tid + 256) >> 2,  ca1 = (tid & 3) * 8;

    // LN2 row stats for this thread's two staging rows (stats accumulated by o-proj)
    const int gr0 = m0 + ra0, gr1 = m0 + ra1;
    const float s0  = rstats[(size_t)gr0 * 2],     q0 = rstats[(size_t)gr0 * 2 + 1];
    const float s1  = rstats[(size_t)gr1 * 2],     q1 = rstats[(size_t)gr1 * 2 + 1];
    const float mean0 = s0 * (1.0f / Dmod);
    const float mean1 = s1 * (1.0f / Dmod);
    const float rstd0 = rsqrtf(q0 * (1.0f / Dmod) - mean0 * mean0 + 1e-5f);
    const float rstd1 = rsqrtf(q1 * (1.0f / Dmod) - mean1 * mean1 + 1e-5f);

    f32x4 acc[4][4] = {};

    for (int k0 = 0; k0 < Dmod; k0 += 32) {
        __syncthreads();
        // A: load x1, apply LN2 in-register, write LDS
        float4 w0 = *(const float4*)(ln2w + k0 + ca0);
        float4 w1 = *(const float4*)(ln2w + k0 + ca0 + 4);
        float4 b0 = *(const float4*)(ln2b + k0 + ca0);
        float4 b1 = *(const float4*)(ln2b + k0 + ca0 + 4);
        float ws[8] = {w0.x, w0.y, w0.z, w0.w, w1.x, w1.y, w1.z, w1.w};
        float bs[8] = {b0.x, b0.y, b0.z, b0.w, b1.x, b1.y, b1.z, b1.w};
        bf16x8 v0 = *(const bf16x8*)(x1 + (size_t)gr0 * Dmod + k0 + ca0);
        bf16x8 v1 = *(const bf16x8*)(x1 + (size_t)gr1 * Dmod + k0 + ca1);
        bf16x8 n0v, n1v;
#pragma unroll
        for (int j = 0; j < 8; ++j) {
            n0v[j] = (__bf16)(((float)v0[j] - mean0) * rstd0 * ws[j] + bs[j]);
            n1v[j] = (__bf16)(((float)v1[j] - mean1) * rstd1 * ws[j] + bs[j]);
        }
        *(bf16x8*)(As + tid * 8)         = n0v;
        *(bf16x8*)(As + (tid + 256) * 8) = n1v;
        glds16(W + (size_t)(n0 + ra0) * Dmod + k0 + ca0, Bs + tid * 8);
        glds16(W + (size_t)(n0 + ra1) * Dmod + k0 + ca1, Bs + (tid + 256) * 8);
        __syncthreads();
        bf16x8 af[4], bfr[4];
#pragma unroll
        for (int mi = 0; mi < 4; ++mi)
            af[mi] = *(const bf16x8*)(As + (mr + mi * 16 + t) * 32 + quad * 8);
#pragma unroll
        for (int ni = 0; ni < 4; ++ni)
            bfr[ni] = *(const bf16x8*)(Bs + (nr + ni * 16 + t) * 32 + quad * 8);
#pragma unroll
        for (int mi = 0; mi < 4; ++mi)
#pragma unroll
            for (int ni = 0; ni < 4; ++ni)
                acc[mi][ni] = __builtin_amdgcn_mfma_f32_16x16x32_bf16(af[mi], bfr[ni], acc[mi][ni], 0, 0, 0);
    }

#pragma unroll
    for (int mi = 0; mi < 4; ++mi) {
        const int row_base = m0 + mr + mi * 16 + quad * 4;
#pragma unroll
        for (int gI = 0; gI < 2; ++gI) {
            const int base = n0 + nr + gI * 32;
            const int hb = (base >> 5) * 16 + t;
            const bool valid = hb < HHALF;
            const float b1 = valid ? fc1_b_[hb] : 0.0f;
            const float b2 = valid ? fc1_b_[HHALF + hb] : 0.0f;
#pragma unroll
            for (int r = 0; r < 4; ++r) {
                float a = acc[mi][2 * gI][r] + b1;
                float c = acc[mi][2 * gI + 1][r] + b2;
                float sw = a / (1.0f + __expf(-a)) * c;
                out[(size_t)(row_base + r) * HC + hb] = (__bf16)sw;
            }
        }
    }
}

// ---------------- Flash attention (r7-frozen) + piggy-backed weight conversion ----------------
// grid (32, 8, Bdim*NSPLIT + REST_Z). z < Bdim*NSPLIT: attention; else: convert wo/wfc1p/wfc2p.
__global__ __launch_bounds__(256) void attn_kernel(
    const __bf16* __restrict__ qk, const __bf16* __restrict__ vt,
    const float* __restrict__ coords,
    __bf16* __restrict__ op, float* __restrict__ lp, int ktper,
    const float* __restrict__ o_w, const float* __restrict__ fc1_w,
    const float* __restrict__ fc2_w,
    __bf16* __restrict__ wo, __bf16* __restrict__ wfc1p,
    __bf16* __restrict__ wfc2p)
{
    constexpr int LD = 72;
    __shared__ __bf16 Ks[64][LD];
    __shared__ __bf16 Vt[64][LD];
    __shared__ __bf16 Ps[64][LD];
    __shared__ float2 kco[64];

    if (blockIdx.z >= Bdim * NSPLIT) {
        // weight-conversion blocks (hidden under attention's idle pipes)
        int cidx = ((blockIdx.z - Bdim * NSPLIT) * 8 + blockIdx.y) * 32 + blockIdx.x;
        int idx = cidx * 256 + threadIdx.x;
        if (idx < SEG1) { wo[idx] = (__bf16)o_w[idx]; return; }
        idx -= SEG1;
        if (idx < SEG2) {
            int n = idx >> 9, k = idx & 511;
            int j = n >> 5, u = n & 31;
            int base = j * 16 + (u & 15);
            float v = 0.0f;
            if (base < HHALF) {
                int hidx = base + ((u & 16) ? HHALF : 0);
                v = fc1_w[(size_t)hidx * 512 + k];
            }
            wfc1p[idx] = (__bf16)v;
            return;
        }
        idx -= SEG2;
        int n = idx / HC, k = idx - n * HC;
        float v = (k < HHALF) ? fc2_w[(size_t)n * HHALF + k] : 0.0f;
        wfc2p[idx] = (__bf16)v;
        return;
    }

    const int qt = blockIdx.x, h = blockIdx.y;
    const int s = blockIdx.z >> 1, b = blockIdx.z & 1;
    const int bh = b * Hn + h;
    const int tid = threadIdx.x;
    const int wave = tid >> 6, lane = tid & 63;
    const int t = lane & 15, quad = lane >> 4;
    const float c1 = 0.125f * 1.44269504f;
    const float d1 = exp2f(-(float)(h + 1)) * 1.44269504f;

    const int qrow = qt * 64 + wave * 16 + t;
    const size_t qbase = (size_t)(b * Nseq + qrow) * 1024 + h * DHd;
    bf16x8 bq0 = *(const bf16x8*)(qk + qbase + quad * 8);
    bf16x8 bq1 = *(const bf16x8*)(qk + qbase + 32 + quad * 8);
    float2 qc = *(const float2*)(coords + (size_t)(b * Nseq + qrow) * 2);
    const float qx = qc.x, qy = qc.y;

    const int sr = tid >> 3, scc = (tid & 7) * 8;
    const __bf16* kbase = qk + (size_t)(b * Nseq) * 1024 + 512 + h * DHd;
    const __bf16* vbase = vt + (size_t)(bh * 64) * Nseq;

    bf16x8 kreg0, kreg1, vreg0, vreg1;
    float2 kcreg = {0.f, 0.f};
    int kn = s * ktper * 64;
    kreg0 = *(const bf16x8*)(kbase + (size_t)(kn + sr) * 1024 + scc);
    kreg1 = *(const bf16x8*)(kbase + (size_t)(kn + sr + 32) * 1024 + scc);
    vreg0 = *(const bf16x8*)(vbase + (size_t)sr * Nseq + kn + scc);
    vreg1 = *(const bf16x8*)(vbase + (size_t)(sr + 32) * Nseq + kn + scc);
    if (tid < 64) kcreg = *(const float2*)(coords + (size_t)(b * Nseq + kn + tid) * 2);

    f32x4 o[4] = {};
    float lrun = 0.0f;

    for (int it = 0; it < ktper; ++it) {
        __syncthreads();
        *(bf16x8*)(&Ks[sr][scc])      = kreg0;
        *(bf16x8*)(&Ks[sr + 32][scc]) = kreg1;
        *(bf16x8*)(&Vt[sr][scc])      = vreg0;
        *(bf16x8*)(&Vt[sr + 32][scc]) = vreg1;
        if (tid < 64) kco[tid] = kcreg;
        __syncthreads();
        if (it + 1 < ktper) {
            const int k2 = kn + 64;
            kreg0 = *(const bf16x8*)(kbase + (size_t)(k2 + sr) * 1024 + scc);
            kreg1 = *(const bf16x8*)(kbase + (size_t)(k2 + sr + 32) * 1024 + scc);
            vreg0 = *(const bf16x8*)(vbase + (size_t)sr * Nseq + k2 + scc);
            vreg1 = *(const bf16x8*)(vbase + (size_t)(sr + 32) * Nseq + k2 + scc);
            if (tid < 64) kcreg = *(const float2*)(coords + (size_t)(b * Nseq + k2 + tid) * 2);
        }

        f32x4 sA[4];
#pragma unroll
        for (int am = 0; am < 4; ++am) {
            bf16x8 a0 = *(const bf16x8*)(&Ks[am * 16 + t][quad * 8]);
            bf16x8 a1 = *(const bf16x8*)(&Ks[am * 16 + t][32 + quad * 8]);
            f32x4 z = {};
            z = __builtin_amdgcn_mfma_f32_16x16x32_bf16(a0, bq0, z, 0, 0, 0);
            sA[am] = __builtin_amdgcn_mfma_f32_16x16x32_bf16(a1, bq1, z, 0, 0, 0);
        }

        float p[4][4];
#pragma unroll
        for (int am = 0; am < 4; ++am)
#pragma unroll
            for (int r = 0; r < 4; ++r) {
                float2 kc = kco[am * 16 + quad * 4 + r];
                float dx = qx - kc.x, dy = qy - kc.y;
                float dist = __builtin_amdgcn_sqrtf(dx * dx + dy * dy);
                float e = __builtin_amdgcn_exp2f(sA[am][r] * c1 - d1 * dist);
                p[am][r] = e;
                lrun += e;
            }

#pragma unroll
        for (int am = 0; am < 4; ++am) {
            bf16x4 pk;
#pragma unroll
            for (int r = 0; r < 4; ++r) pk[r] = (__bf16)p[am][r];
            *(bf16x4*)(&Ps[wave * 16 + t][am * 16 + quad * 4]) = pk;
        }

        bf16x8 ap0 = *(const bf16x8*)(&Ps[wave * 16 + t][quad * 8]);
        bf16x8 ap1 = *(const bf16x8*)(&Ps[wave * 16 + t][32 + quad * 8]);
#pragma unroll
        for (int ct = 0; ct < 4; ++ct) {
            bf16x8 bv0 = *(const bf16x8*)(&Vt[ct * 16 + t][quad * 8]);
            bf16x8 bv1 = *(const bf16x8*)(&Vt[ct * 16 + t][32 + quad * 8]);
            o[ct] = __builtin_amdgcn_mfma_f32_16x16x32_bf16(ap0, bv0, o[ct], 0, 0, 0);
            o[ct] = __builtin_amdgcn_mfma_f32_16x16x32_bf16(ap1, bv1, o[ct], 0, 0, 0);
        }
        kn += 64;
    }

    lrun += __shfl_xor(lrun, 16, 64);
    lrun += __shfl_xor(lrun, 32, 64);
    if (quad == 0)
        lp[(((size_t)s * Bdim + b) * Hn + h) * Nseq + qt * 64 + wave * 16 + t] = lrun;

    const int orow_base = qt * 64 + wave * 16 + quad * 4;
#pragma unroll
    for (int ct = 0; ct < 4; ++ct)
#pragma unroll
        for (int r = 0; r < 4; ++r) {
            size_t row = (size_t)s * ROWS + b * Nseq + orow_base + r;
            op[row * Dmod + h * DHd + ct * 16 + t] = (__bf16)o[ct][r];
        }
}

// ---------------- launch ----------------
extern "C" void kernel_launch(void* const* d_in, const int* in_sizes, int n_in,
                              void* d_out, int out_size, void* d_ws, size_t ws_size,
                              hipStream_t stream)
{
    (void)in_sizes; (void)n_in; (void)out_size; (void)ws_size;
    const float* x      = (const float*)d_in[0];
    const float* coords = (const float*)d_in[1];
    const float* q_w    = (const float*)d_in[2];
    const float* q_b    = (const float*)d_in[3];
    const float* k_w    = (const float*)d_in[4];
    const float* k_b    = (const float*)d_in[5];
    const float* v_w    = (const float*)d_in[6];
    const float* v_b    = (const float*)d_in[7];
    const float* o_w    = (const float*)d_in[8];
    const float* o_b    = (const float*)d_in[9];
    const float* gamma1 = (const float*)d_in[10];
    const float* ln1_w  = (const float*)d_in[11];
    const float* ln1_b  = (const float*)d_in[12];
    const float* fc1_w  = (const float*)d_in[13];
    const float* fc1_b  = (const float*)d_in[14];
    const float* fc2_w  = (const float*)d_in[15];
    const float* fc2_b  = (const float*)d_in[16];
    const float* gamma2 = (const float*)d_in[17];
    const float* ln2_w  = (const float*)d_in[18];
    const float* ln2_b  = (const float*)d_in[19];

    size_t off = 0;
    auto alloc = [&](size_t bytes) {
        void* p = (char*)d_ws + off;
        off += (bytes + 255) & ~(size_t)255;
        return p;
    };
    __bf16* wqkv  = (__bf16*)alloc((size_t)1536 * 512 * 2);
    __bf16* wo    = (__bf16*)alloc((size_t)512 * 512 * 2);
    __bf16* wfc1p = (__bf16*)alloc((size_t)NPACK * 512 * 2);
    __bf16* wfc2p = (__bf16*)alloc((size_t)512 * HC * 2);
    __bf16* xn    = (__bf16*)alloc((size_t)ROWS * Dmod * 2);
    __bf16* qkb   = (__bf16*)alloc((size_t)ROWS * 1024 * 2);
    __bf16* vtg   = (__bf16*)alloc((size_t)Bdim * Hn * DHd * Nseq * 2);
    __bf16* x1    = (__bf16*)alloc((size_t)ROWS * Dmod * 2);   // bf16 residual stream
    __bf16* hcomb = (__bf16*)alloc((size_t)ROWS * HC * 2);
    __bf16* opb   = (__bf16*)alloc((size_t)NSPLIT * ROWS * Dmod * 2);
    float*  lpb   = (float*)alloc((size_t)NSPLIT * Bdim * Hn * Nseq * 4);
    float*  rstats = (float*)alloc((size_t)ROWS * 2 * 4);      // per-row sum, sumsq of x1

    // prep: wqkv conversion + zero rstats + LN1
    prep_kernel<<<WQKV_BLOCKS + ZERO_BLOCKS + ROWS, 256, 0, stream>>>(
        q_w, k_w, v_w, wqkv, x, ln1_w, ln1_b, xn, rstats);

    // fused QKV (V written transposed)
    qkv_gemm128<<<dim3(ROWS / 128, 12), 256, 0, stream>>>(xn, wqkv, q_b, k_b, v_b, qkb, vtg);

    // attention (split-K=2) + piggy-backed wo/wfc1p/wfc2p conversion
    attn_kernel<<<dim3(Nseq / 64, Hn, Bdim * NSPLIT + REST_Z), 256, 0, stream>>>(
        qkb, vtg, coords, opb, lpb, Nseq / 64 / NSPLIT,
        o_w, fc1_w, fc2_w, wo, wfc1p, wfc2p);

    // O projection (+fused split-K merge) + residual1 -> x1 (bf16) + LN2 row-stats
    gemm_res<0><<<dim3(ROWS / 64, Dmod / 64), 512, 0, stream>>>(
        nullptr, Dmod, opb, lpb, wo, Dmod, o_b, Dmod, (void*)x1, (const void*)x,
        gamma1, rstats);

    // fc1 (+fused LN2 in A-staging) + fused SwiGLU -> hcomb
    fc1_gemm128<<<dim3(ROWS / 128, NPACK / 128), 256, 0, stream>>>(
        x1, rstats, ln2_w, ln2_b, wfc1p, fc1_b, hcomb);

    // fc2 + residual2 -> d_out (fp32)
    gemm_res<1><<<dim3(ROWS / 64, Dmod / 64), 512, 0, stream>>>(
        hcomb, HC, nullptr, nullptr, wfc2p, HC, fc2_b, HC, d_out, (const void*)x1,
        gamma2, nullptr);
}

// Round 14
// 210.987 us; speedup vs baseline: 1.0379x; 1.0379x over previous
//
#include <hip/hip_runtime.h>
#include <math.h>

#define Bdim  2
#define Nseq  2048
#define Dmod  512
#define Hn    8
#define DHd   64
#define HID   2730
#define HHALF 1365
#define HC    1408      // combined hidden, padded (22*64)
#define NPACK 2816      // packed fc1 output cols (2*HC)
#define ROWS  4096      // Bdim*Nseq
#define NSPLIT 2        // attention split-K (r7-frozen config)

typedef __bf16 bf16x8 __attribute__((ext_vector_type(8)));
typedef __bf16 bf16x4 __attribute__((ext_vector_type(4)));
typedef __bf16 bf16x2 __attribute__((ext_vector_type(2)));
typedef float  f32x4  __attribute__((ext_vector_type(4)));

__device__ __forceinline__ void glds16(const __bf16* g, __bf16* l) {
    __builtin_amdgcn_global_load_lds(
        (const __attribute__((address_space(1))) void*)g,
        (__attribute__((address_space(3))) void*)l, 16, 0, 0);
}

// weight segment sizes
#define SEG0 (1536*512)    // wqkv
#define SEG1 (512*512)     // wo
#define SEG2 (NPACK*512)   // wfc1p
#define SEG3 (512*HC)      // wfc2p
#define WQKV_BLOCKS (SEG0 / 256)                   // 3072
#define REST_BLOCKS ((SEG1 + SEG2 + SEG3) / 256)   // 9472
#define REST_Z (REST_BLOCKS / (32 * 8))            // 37

// ---------------- LN core (row=512, 256 threads) ----------------
__device__ __forceinline__ void ln_core(
    int tid, float vx, float vy, const float* __restrict__ w,
    const float* __restrict__ b, __bf16* __restrict__ orow)
{
    float s  = vx + vy;
    float sq = vx * vx + vy * vy;
#pragma unroll
    for (int m = 1; m < 64; m <<= 1) {
        s  += __shfl_xor(s, m, 64);
        sq += __shfl_xor(sq, m, 64);
    }
    __shared__ float ss[4], ssq[4];
    const int wv = tid >> 6;
    if ((tid & 63) == 0) { ss[wv] = s; ssq[wv] = sq; }
    __syncthreads();
    s  = ss[0] + ss[1] + ss[2] + ss[3];
    sq = ssq[0] + ssq[1] + ssq[2] + ssq[3];
    const float mean = s * (1.0f / Dmod);
    const float var  = sq * (1.0f / Dmod) - mean * mean;
    const float rstd = rsqrtf(var + 1e-5f);
    float2 wv2 = *(const float2*)(w + tid * 2);
    float2 bv2 = *(const float2*)(b + tid * 2);
    orow[0] = (__bf16)((vx - mean) * rstd * wv2.x + bv2.x);
    orow[1] = (__bf16)((vy - mean) * rstd * wv2.y + bv2.y);
}

// ---------------- prep: wqkv conversion + LN1 ----------------
__global__ __launch_bounds__(256) void prep_kernel(
    const float* __restrict__ q_w, const float* __restrict__ k_w,
    const float* __restrict__ v_w, __bf16* __restrict__ wqkv,
    const float* __restrict__ x, const float* __restrict__ ln1w,
    const float* __restrict__ ln1b, __bf16* __restrict__ xn)
{
    if (blockIdx.x < WQKV_BLOCKS) {
        int idx = blockIdx.x * 256 + threadIdx.x;
        int n = idx >> 9, k = idx & 511;
        float v = (n < 512) ? q_w[n * 512 + k]
                : (n < 1024) ? k_w[(n - 512) * 512 + k]
                : v_w[(n - 1024) * 512 + k];
        wqkv[idx] = (__bf16)v;
        return;
    }
    const int row = blockIdx.x - WQKV_BLOCKS, tid = threadIdx.x;
    float2 v = *(const float2*)(x + (size_t)row * Dmod + tid * 2);
    ln_core(tid, v.x, v.y, ln1w, ln1b, xn + (size_t)row * Dmod + tid * 2);
}

// ---------------- LN2 (bf16 input x1) ----------------
__global__ __launch_bounds__(256) void ln_kernel_bf16(
    const __bf16* __restrict__ x, const float* __restrict__ w,
    const float* __restrict__ b, __bf16* __restrict__ out)
{
    const int row = blockIdx.x, tid = threadIdx.x;
    bf16x2 v2 = *(const bf16x2*)(x + (size_t)row * Dmod + tid * 2);
    ln_core(tid, (float)v2[0], (float)v2[1], w, b, out + (size_t)row * Dmod + tid * 2);
}

// ---------------- 64x64 residual GEMM, 8 waves, K-parallel x2, XOR-swizzled LDS ----------------
// MODE 0 (o-proj): A = merged attention partials (op0+op1)*rcp(l0+l1); res fp32; out bf16.
// MODE 1 (fc2):    A = direct bf16 via glds16;                        res bf16; out fp32.
template<int MODE>
__global__ __launch_bounds__(512) void gemm_res(
    const __bf16* __restrict__ A, int lda,
    const __bf16* __restrict__ opA, const float* __restrict__ lpA,
    const __bf16* __restrict__ Bw, int ldb,
    const float* __restrict__ bias, int K,
    void* __restrict__ outp, const void* __restrict__ resp,
    const float* __restrict__ g)
{
    __shared__ __bf16 smem[2 * 64 * 64];
    __bf16* As = smem;
    __bf16* Bs = smem + 64 * 64;
    const int tid  = threadIdx.x;
    const int wave = tid >> 6, lane = tid & 63;
    const int t    = lane & 15, quad = lane >> 4;
    const int kg   = wave >> 2, wv = wave & 3;
    const int m0   = blockIdx.x * 64;
    const int n0   = blockIdx.y * 64;

    const int srow = tid >> 3;
    const int gch  = ((tid & 7) ^ (srow & 7)) * 8;
    const int grow = m0 + srow;
    const int bI   = grow >> 11, nn = grow & 2047;
    const __bf16* aptr = A  + (size_t)grow * lda + gch;
    const __bf16* bptr = Bw + (size_t)(n0 + srow) * ldb + gch;

    const int arow = wv * 16 + t;
    const int aoff = arow * 64 + (((kg * 4 + quad) ^ (arow & 7)) * 8);
    int boffs[4];
#pragma unroll
    for (int ct = 0; ct < 4; ++ct) {
        int brow = ct * 16 + t;
        boffs[ct] = brow * 64 + (((kg * 4 + quad) ^ (brow & 7)) * 8);
    }

    f32x4 acc[4] = {};
    for (int k0 = 0; k0 < K; k0 += 64) {
        __syncthreads();
        if (MODE == 0) {
            const int kk = k0 + gch;
            const int h = kk >> 6;
            float l = lpA[((size_t)(bI * Hn) + h) * Nseq + nn]
                    + lpA[((size_t)((Bdim + bI) * Hn) + h) * Nseq + nn];
            float rl = __builtin_amdgcn_rcpf(l);
            bf16x8 a0 = *(const bf16x8*)(opA + (size_t)grow * Dmod + kk);
            bf16x8 a1 = *(const bf16x8*)(opA + ((size_t)ROWS + grow) * Dmod + kk);
            bf16x8 mg;
#pragma unroll
            for (int j = 0; j < 8; ++j)
                mg[j] = (__bf16)(((float)a0[j] + (float)a1[j]) * rl);
            *(bf16x8*)(As + tid * 8) = mg;
        } else {
            glds16(aptr + k0, As + tid * 8);
        }
        glds16(bptr + k0, Bs + tid * 8);
        __syncthreads();
        bf16x8 a = *(const bf16x8*)(As + aoff);
#pragma unroll
        for (int ct = 0; ct < 4; ++ct) {
            bf16x8 b = *(const bf16x8*)(Bs + boffs[ct]);
            acc[ct] = __builtin_amdgcn_mfma_f32_16x16x32_bf16(a, b, acc[ct], 0, 0, 0);
        }
    }

    __syncthreads();
    if (kg == 1) {
        float* dst = (float*)smem + ((size_t)wv * 64 + lane) * 16;
#pragma unroll
        for (int ct = 0; ct < 4; ++ct) *(f32x4*)(dst + ct * 4) = acc[ct];
    }
    __syncthreads();
    if (kg == 0) {
        const float* src = (const float*)smem + ((size_t)wv * 64 + lane) * 16;
        const int row_base = m0 + wv * 16 + quad * 4;
#pragma unroll
        for (int ct = 0; ct < 4; ++ct) {
            f32x4 other = *(const f32x4*)(src + ct * 4);
            const int col = n0 + ct * 16 + t;
            const float bb = bias[col];
#pragma unroll
            for (int r = 0; r < 4; ++r) {
                const int row = row_base + r;
                const float v = (acc[ct][r] + other[r] + bb) * g[col];
                if (MODE == 0) {
                    float rv = ((const float*)resp)[(size_t)row * Dmod + col];
                    ((__bf16*)outp)[(size_t)row * Dmod + col] = (__bf16)(rv + v);
                } else {
                    float rv = (float)((const __bf16*)resp)[(size_t)row * Dmod + col];
                    ((float*)outp)[(size_t)row * Dmod + col] = rv + v;
                }
            }
        }
    }
}

// ---------------- 128x128 QKV GEMM (BK=32); V written transposed via LDS ----------------
#define LDT 136
__global__ __launch_bounds__(256) void qkv_gemm128(
    const __bf16* __restrict__ A, const __bf16* __restrict__ W,
    const float* __restrict__ qb_, const float* __restrict__ kb_,
    const float* __restrict__ vb_,
    __bf16* __restrict__ qk, __bf16* __restrict__ vtg)
{
    __shared__ __bf16 smem[64 * LDT];
    __bf16* As = smem;
    __bf16* Bs = smem + 4096;
    const int tid  = threadIdx.x;
    const int wave = tid >> 6, lane = tid & 63;
    const int t    = lane & 15, quad = lane >> 4;
    const int m0   = blockIdx.x * 128, n0 = blockIdx.y * 128;
    const int mr   = (wave & 1) * 64,  nr = (wave >> 1) * 64;
    const int ra0 = tid >> 2,          ca0 = (tid & 3) * 8;
    const int ra1 = (tid + 256) >> 2,  ca1 = (tid & 3) * 8;

    f32x4 acc[4][4] = {};

    for (int k0 = 0; k0 < Dmod; k0 += 32) {
        __syncthreads();
        glds16(A + (size_t)(m0 + ra0) * Dmod + k0 + ca0, As + tid * 8);
        glds16(A + (size_t)(m0 + ra1) * Dmod + k0 + ca1, As + (tid + 256) * 8);
        glds16(W + (size_t)(n0 + ra0) * Dmod + k0 + ca0, Bs + tid * 8);
        glds16(W + (size_t)(n0 + ra1) * Dmod + k0 + ca1, Bs + (tid + 256) * 8);
        __syncthreads();
        bf16x8 af[4], bfr[4];
#pragma unroll
        for (int mi = 0; mi < 4; ++mi)
            af[mi] = *(const bf16x8*)(As + (mr + mi * 16 + t) * 32 + quad * 8);
#pragma unroll
        for (int ni = 0; ni < 4; ++ni)
            bfr[ni] = *(const bf16x8*)(Bs + (nr + ni * 16 + t) * 32 + quad * 8);
#pragma unroll
        for (int mi = 0; mi < 4; ++mi)
#pragma unroll
            for (int ni = 0; ni < 4; ++ni)
                acc[mi][ni] = __builtin_amdgcn_mfma_f32_16x16x32_bf16(af[mi], bfr[ni], acc[mi][ni], 0, 0, 0);
    }

    const int y = blockIdx.y;
    if (y < 8) {
#pragma unroll
        for (int mi = 0; mi < 4; ++mi) {
            const int row_base = m0 + mr + mi * 16 + quad * 4;
#pragma unroll
            for (int ni = 0; ni < 4; ++ni) {
                const int col = n0 + nr + ni * 16 + t;
                const float bb = (col < 512) ? qb_[col] : kb_[col - 512];
#pragma unroll
                for (int r = 0; r < 4; ++r)
                    qk[(size_t)(row_base + r) * 1024 + col] = (__bf16)(acc[mi][ni][r] + bb);
            }
        }
    } else {
        const int tok0 = m0 & 2047;
        const int bI   = m0 >> 11;
#pragma unroll
        for (int half = 0; half < 2; ++half) {
            __syncthreads();
            if ((wave >> 1) == half) {
#pragma unroll
                for (int ni = 0; ni < 4; ++ni) {
                    const int dh = ni * 16 + t;
                    const float bb = vb_[(y - 8) * 128 + half * 64 + dh];
#pragma unroll
                    for (int mi = 0; mi < 4; ++mi) {
                        const int n = mr + mi * 16 + quad * 4;
                        bf16x4 pk;
#pragma unroll
                        for (int r = 0; r < 4; ++r) pk[r] = (__bf16)(acc[mi][ni][r] + bb);
                        *(bf16x4*)(smem + dh * LDT + n) = pk;
                    }
                }
            }
            __syncthreads();
            const int hh = (y - 8) * 2 + half;
            const size_t rowbase = (size_t)(bI * 8 + hh) * 64;
#pragma unroll
            for (int j = 0; j < 4; ++j) {
                int chunk = tid + j * 256;
                int dr = chunk >> 4, cc = (chunk & 15) * 8;
                bf16x8 vv = *(const bf16x8*)(smem + dr * LDT + cc);
                *(bf16x8*)(vtg + (rowbase + dr) * Nseq + tok0 + cc) = vv;
            }
        }
    }
}

// ---------------- 128x128 fc1 GEMM (BK=32) with fused SwiGLU epilogue ----------------
__global__ __launch_bounds__(256) void fc1_gemm128(
    const __bf16* __restrict__ A, const __bf16* __restrict__ W,
    const float* __restrict__ fc1_b_, __bf16* __restrict__ out)
{
    __shared__ __bf16 As[128 * 32];
    __shared__ __bf16 Bs[128 * 32];
    const int tid  = threadIdx.x;
    const int wave = tid >> 6, lane = tid & 63;
    const int t    = lane & 15, quad = lane >> 4;
    const int m0   = blockIdx.x * 128, n0 = blockIdx.y * 128;
    const int mr   = (wave & 1) * 64,  nr = (wave >> 1) * 64;
    const int ra0 = tid >> 2,          ca0 = (tid & 3) * 8;
    const int ra1 = (tid + 256) >> 2,  ca1 = (tid & 3) * 8;

    f32x4 acc[4][4] = {};

    for (int k0 = 0; k0 < Dmod; k0 += 32) {
        __syncthreads();
        glds16(A + (size_t)(m0 + ra0) * Dmod + k0 + ca0, As + tid * 8);
        glds16(A + (size_t)(m0 + ra1) * Dmod + k0 + ca1, As + (tid + 256) * 8);
        glds16(W + (size_t)(n0 + ra0) * Dmod + k0 + ca0, Bs + tid * 8);
        glds16(W + (size_t)(n0 + ra1) * Dmod + k0 + ca1, Bs + (tid + 256) * 8);
        __syncthreads();
        bf16x8 af[4], bfr[4];
#pragma unroll
        for (int mi = 0; mi < 4; ++mi)
            af[mi] = *(const bf16x8*)(As + (mr + mi * 16 + t) * 32 + quad * 8);
#pragma unroll
        for (int ni = 0; ni < 4; ++ni)
            bfr[ni] = *(const bf16x8*)(Bs + (nr + ni * 16 + t) * 32 + quad * 8);
#pragma unroll
        for (int mi = 0; mi < 4; ++mi)
#pragma unroll
            for (int ni = 0; ni < 4; ++ni)
                acc[mi][ni] = __builtin_amdgcn_mfma_f32_16x16x32_bf16(af[mi], bfr[ni], acc[mi][ni], 0, 0, 0);
    }

#pragma unroll
    for (int mi = 0; mi < 4; ++mi) {
        const int row_base = m0 + mr + mi * 16 + quad * 4;
#pragma unroll
        for (int gI = 0; gI < 2; ++gI) {
            const int base = n0 + nr + gI * 32;
            const int hb = (base >> 5) * 16 + t;
            const bool valid = hb < HHALF;
            const float b1 = valid ? fc1_b_[hb] : 0.0f;
            const float b2 = valid ? fc1_b_[HHALF + hb] : 0.0f;
#pragma unroll
            for (int r = 0; r < 4; ++r) {
                float a = acc[mi][2 * gI][r] + b1;
                float c = acc[mi][2 * gI + 1][r] + b2;
                float sw = a / (1.0f + __expf(-a)) * c;
                out[(size_t)(row_base + r) * HC + hb] = (__bf16)sw;
            }
        }
    }
}

// ---------------- Flash attention (r7-frozen) + piggy-backed weight conversion ----------------
// grid (32, 8, Bdim*NSPLIT + REST_Z). z < Bdim*NSPLIT: attention; else: convert wo/wfc1p/wfc2p.
// [r13-proven: conversion absorbed for free — attn dispatch duration unchanged]
__global__ __launch_bounds__(256) void attn_kernel(
    const __bf16* __restrict__ qk, const __bf16* __restrict__ vt,
    const float* __restrict__ coords,
    __bf16* __restrict__ op, float* __restrict__ lp, int ktper,
    const float* __restrict__ o_w, const float* __restrict__ fc1_w,
    const float* __restrict__ fc2_w,
    __bf16* __restrict__ wo, __bf16* __restrict__ wfc1p,
    __bf16* __restrict__ wfc2p)
{
    constexpr int LD = 72;
    __shared__ __bf16 Ks[64][LD];
    __shared__ __bf16 Vt[64][LD];
    __shared__ __bf16 Ps[64][LD];
    __shared__ float2 kco[64];

    if (blockIdx.z >= Bdim * NSPLIT) {
        int cidx = ((blockIdx.z - Bdim * NSPLIT) * 8 + blockIdx.y) * 32 + blockIdx.x;
        int idx = cidx * 256 + threadIdx.x;
        if (idx < SEG1) { wo[idx] = (__bf16)o_w[idx]; return; }
        idx -= SEG1;
        if (idx < SEG2) {
            int n = idx >> 9, k = idx & 511;
            int j = n >> 5, u = n & 31;
            int base = j * 16 + (u & 15);
            float v = 0.0f;
            if (base < HHALF) {
                int hidx = base + ((u & 16) ? HHALF : 0);
                v = fc1_w[(size_t)hidx * 512 + k];
            }
            wfc1p[idx] = (__bf16)v;
            return;
        }
        idx -= SEG2;
        int n = idx / HC, k = idx - n * HC;
        float v = (k < HHALF) ? fc2_w[(size_t)n * HHALF + k] : 0.0f;
        wfc2p[idx] = (__bf16)v;
        return;
    }

    const int qt = blockIdx.x, h = blockIdx.y;
    const int s = blockIdx.z >> 1, b = blockIdx.z & 1;
    const int bh = b * Hn + h;
    const int tid = threadIdx.x;
    const int wave = tid >> 6, lane = tid & 63;
    const int t = lane & 15, quad = lane >> 4;
    const float c1 = 0.125f * 1.44269504f;
    const float d1 = exp2f(-(float)(h + 1)) * 1.44269504f;

    const int qrow = qt * 64 + wave * 16 + t;
    const size_t qbase = (size_t)(b * Nseq + qrow) * 1024 + h * DHd;
    bf16x8 bq0 = *(const bf16x8*)(qk + qbase + quad * 8);
    bf16x8 bq1 = *(const bf16x8*)(qk + qbase + 32 + quad * 8);
    float2 qc = *(const float2*)(coords + (size_t)(b * Nseq + qrow) * 2);
    const float qx = qc.x, qy = qc.y;

    const int sr = tid >> 3, scc = (tid & 7) * 8;
    const __bf16* kbase = qk + (size_t)(b * Nseq) * 1024 + 512 + h * DHd;
    const __bf16* vbase = vt + (size_t)(bh * 64) * Nseq;

    bf16x8 kreg0, kreg1, vreg0, vreg1;
    float2 kcreg = {0.f, 0.f};
    int kn = s * ktper * 64;
    kreg0 = *(const bf16x8*)(kbase + (size_t)(kn + sr) * 1024 + scc);
    kreg1 = *(const bf16x8*)(kbase + (size_t)(kn + sr + 32) * 1024 + scc);
    vreg0 = *(const bf16x8*)(vbase + (size_t)sr * Nseq + kn + scc);
    vreg1 = *(const bf16x8*)(vbase + (size_t)(sr + 32) * Nseq + kn + scc);
    if (tid < 64) kcreg = *(const float2*)(coords + (size_t)(b * Nseq + kn + tid) * 2);

    f32x4 o[4] = {};
    float lrun = 0.0f;

    for (int it = 0; it < ktper; ++it) {
        __syncthreads();
        *(bf16x8*)(&Ks[sr][scc])      = kreg0;
        *(bf16x8*)(&Ks[sr + 32][scc]) = kreg1;
        *(bf16x8*)(&Vt[sr][scc])      = vreg0;
        *(bf16x8*)(&Vt[sr + 32][scc]) = vreg1;
        if (tid < 64) kco[tid] = kcreg;
        __syncthreads();
        if (it + 1 < ktper) {
            const int k2 = kn + 64;
            kreg0 = *(const bf16x8*)(kbase + (size_t)(k2 + sr) * 1024 + scc);
            kreg1 = *(const bf16x8*)(kbase + (size_t)(k2 + sr + 32) * 1024 + scc);
            vreg0 = *(const bf16x8*)(vbase + (size_t)sr * Nseq + k2 + scc);
            vreg1 = *(const bf16x8*)(vbase + (size_t)(sr + 32) * Nseq + k2 + scc);
            if (tid < 64) kcreg = *(const float2*)(coords + (size_t)(b * Nseq + k2 + tid) * 2);
        }

        f32x4 sA[4];
#pragma unroll
        for (int am = 0; am < 4; ++am) {
            bf16x8 a0 = *(const bf16x8*)(&Ks[am * 16 + t][quad * 8]);
            bf16x8 a1 = *(const bf16x8*)(&Ks[am * 16 + t][32 + quad * 8]);
            f32x4 z = {};
            z = __builtin_amdgcn_mfma_f32_16x16x32_bf16(a0, bq0, z, 0, 0, 0);
            sA[am] = __builtin_amdgcn_mfma_f32_16x16x32_bf16(a1, bq1, z, 0, 0, 0);
        }

        float p[4][4];
#pragma unroll
        for (int am = 0; am < 4; ++am)
#pragma unroll
            for (int r = 0; r < 4; ++r) {
                float2 kc = kco[am * 16 + quad * 4 + r];
                float dx = qx - kc.x, dy = qy - kc.y;
                float dist = __builtin_amdgcn_sqrtf(dx * dx + dy * dy);
                float e = __builtin_amdgcn_exp2f(sA[am][r] * c1 - d1 * dist);
                p[am][r] = e;
                lrun += e;
            }

#pragma unroll
        for (int am = 0; am < 4; ++am) {
            bf16x4 pk;
#pragma unroll
            for (int r = 0; r < 4; ++r) pk[r] = (__bf16)p[am][r];
            *(bf16x4*)(&Ps[wave * 16 + t][am * 16 + quad * 4]) = pk;
        }

        bf16x8 ap0 = *(const bf16x8*)(&Ps[wave * 16 + t][quad * 8]);
        bf16x8 ap1 = *(const bf16x8*)(&Ps[wave * 16 + t][32 + quad * 8]);
#pragma unroll
        for (int ct = 0; ct < 4; ++ct) {
            bf16x8 bv0 = *(const bf16x8*)(&Vt[ct * 16 + t][quad * 8]);
            bf16x8 bv1 = *(const bf16x8*)(&Vt[ct * 16 + t][32 + quad * 8]);
            o[ct] = __builtin_amdgcn_mfma_f32_16x16x32_bf16(ap0, bv0, o[ct], 0, 0, 0);
            o[ct] = __builtin_amdgcn_mfma_f32_16x16x32_bf16(ap1, bv1, o[ct], 0, 0, 0);
        }
        kn += 64;
    }

    lrun += __shfl_xor(lrun, 16, 64);
    lrun += __shfl_xor(lrun, 32, 64);
    if (quad == 0)
        lp[(((size_t)s * Bdim + b) * Hn + h) * Nseq + qt * 64 + wave * 16 + t] = lrun;

    const int orow_base = qt * 64 + wave * 16 + quad * 4;
#pragma unroll
    for (int ct = 0; ct < 4; ++ct)
#pragma unroll
        for (int r = 0; r < 4; ++r) {
            size_t row = (size_t)s * ROWS + b * Nseq + orow_base + r;
            op[row * Dmod + h * DHd + ct * 16 + t] = (__bf16)o[ct][r];
        }
}

// ---------------- launch ----------------
extern "C" void kernel_launch(void* const* d_in, const int* in_sizes, int n_in,
                              void* d_out, int out_size, void* d_ws, size_t ws_size,
                              hipStream_t stream)
{
    (void)in_sizes; (void)n_in; (void)out_size; (void)ws_size;
    const float* x      = (const float*)d_in[0];
    const float* coords = (const float*)d_in[1];
    const float* q_w    = (const float*)d_in[2];
    const float* q_b    = (const float*)d_in[3];
    const float* k_w    = (const float*)d_in[4];
    const float* k_b    = (const float*)d_in[5];
    const float* v_w    = (const float*)d_in[6];
    const float* v_b    = (const float*)d_in[7];
    const float* o_w    = (const float*)d_in[8];
    const float* o_b    = (const float*)d_in[9];
    const float* gamma1 = (const float*)d_in[10];
    const float* ln1_w  = (const float*)d_in[11];
    const float* ln1_b  = (const float*)d_in[12];
    const float* fc1_w  = (const float*)d_in[13];
    const float* fc1_b  = (const float*)d_in[14];
    const float* fc2_w  = (const float*)d_in[15];
    const float* fc2_b  = (const float*)d_in[16];
    const float* gamma2 = (const float*)d_in[17];
    const float* ln2_w  = (const float*)d_in[18];
    const float* ln2_b  = (const float*)d_in[19];

    size_t off = 0;
    auto alloc = [&](size_t bytes) {
        void* p = (char*)d_ws + off;
        off += (bytes + 255) & ~(size_t)255;
        return p;
    };
    __bf16* wqkv  = (__bf16*)alloc((size_t)1536 * 512 * 2);
    __bf16* wo    = (__bf16*)alloc((size_t)512 * 512 * 2);
    __bf16* wfc1p = (__bf16*)alloc((size_t)NPACK * 512 * 2);
    __bf16* wfc2p = (__bf16*)alloc((size_t)512 * HC * 2);
    __bf16* xn    = (__bf16*)alloc((size_t)ROWS * Dmod * 2);
    __bf16* xn2   = (__bf16*)alloc((size_t)ROWS * Dmod * 2);
    __bf16* qkb   = (__bf16*)alloc((size_t)ROWS * 1024 * 2);
    __bf16* vtg   = (__bf16*)alloc((size_t)Bdim * Hn * DHd * Nseq * 2);
    __bf16* x1    = (__bf16*)alloc((size_t)ROWS * Dmod * 2);   // bf16 residual stream
    __bf16* hcomb = (__bf16*)alloc((size_t)ROWS * HC * 2);
    __bf16* opb   = (__bf16*)alloc((size_t)NSPLIT * ROWS * Dmod * 2);
    float*  lpb   = (float*)alloc((size_t)NSPLIT * Bdim * Hn * Nseq * 4);

    // prep: wqkv conversion + LN1 (wo/wfc1p/wfc2p conversion rides inside attn)
    prep_kernel<<<WQKV_BLOCKS + ROWS, 256, 0, stream>>>(
        q_w, k_w, v_w, wqkv, x, ln1_w, ln1_b, xn);

    // fused QKV (V written transposed)
    qkv_gemm128<<<dim3(ROWS / 128, 12), 256, 0, stream>>>(xn, wqkv, q_b, k_b, v_b, qkb, vtg);

    // attention (split-K=2) + piggy-backed wo/wfc1p/wfc2p conversion
    attn_kernel<<<dim3(Nseq / 64, Hn, Bdim * NSPLIT + REST_Z), 256, 0, stream>>>(
        qkb, vtg, coords, opb, lpb, Nseq / 64 / NSPLIT,
        o_w, fc1_w, fc2_w, wo, wfc1p, wfc2p);

    // O projection (+fused split-K merge) + residual1 -> x1 (bf16)
    gemm_res<0><<<dim3(ROWS / 64, Dmod / 64), 512, 0, stream>>>(
        nullptr, Dmod, opb, lpb, wo, Dmod, o_b, Dmod, (void*)x1, (const void*)x, gamma1);

    // LN2
    ln_kernel_bf16<<<ROWS, 256, 0, stream>>>(x1, ln2_w, ln2_b, xn2);

    // fc1 + fused SwiGLU -> hcomb
    fc1_gemm128<<<dim3(ROWS / 128, NPACK / 128), 256, 0, stream>>>(xn2, wfc1p, fc1_b, hcomb);

    // fc2 + residual2 -> d_out (fp32)
    gemm_res<1><<<dim3(ROWS / 64, Dmod / 64), 512, 0, stream>>>(
        hcomb, HC, nullptr, nullptr, wfc2p, HC, fc2_b, HC, d_out, (const void*)x1, gamma2);
}